// Round 18
// baseline (401.978 us; speedup 1.0000x reference)
//
#include <hip/hip_runtime.h>
#include <hip/hip_bf16.h>

typedef __hip_bfloat16 hbf16;
typedef unsigned short u16t;
typedef __attribute__((ext_vector_type(8))) short bf16x8;
typedef __attribute__((ext_vector_type(4))) float f32x4;

#define WSZ 5
#define CC 48
#define C3 144
#define HDIM 400
#define NWH 80
#define SH 2
#define ITERS 2      // windows per block = 2 * ITERS (r18: 4->2 to halve drain tail)
#define YROWS 57
#define YW 152   // s_y row stride (halfwords); 304 B, mult 16, 2-way max
#define WTW 56   // s_wT row stride; 112 B, mult 16
#define PW 40    // s_P / s_x1T row stride; 80 B, mult 16

__device__ __forceinline__ u16t f2b(float x) {
    union { hbf16 h; u16t u; } c;
    c.h = __float2bfloat16(x);
    return c.u;
}
__device__ __forceinline__ unsigned pk2(float lo, float hi) {
    return ((unsigned)f2b(hi) << 16) | f2b(lo);
}
// 16-lane (DPP row) butterfly sum — pure VALU, no LDS pipe (verified r12/r13).
__device__ __forceinline__ float dpp_add16(float x) {
    int t;
    t = __builtin_amdgcn_update_dpp(0, __float_as_int(x), 0xB1, 0xF, 0xF, true);   // quad_perm xor1
    x += __int_as_float(t);
    t = __builtin_amdgcn_update_dpp(0, __float_as_int(x), 0x4E, 0xF, 0xF, true);   // quad_perm xor2
    x += __int_as_float(t);
    t = __builtin_amdgcn_update_dpp(0, __float_as_int(x), 0x141, 0xF, 0xF, true);  // row_half_mirror
    x += __int_as_float(t);
    t = __builtin_amdgcn_update_dpp(0, __float_as_int(x), 0x140, 0xF, 0xF, true);  // row_mirror
    x += __int_as_float(t);
    return x;
}

// r18 = r13 (champion, reproduced twice) + two isolated micro levers:
//  (a) vT transpose-write during softmax on the w4==3 wave + zero-init s_x1T
//      (numerics proven in r16; r16's regression was the passthrough move,
//      which is NOT repeated here) -> PV1 vfr = one ds_read_b128.
//  (b) ITERS 4->2: halves block duration -> halves end-of-grid drain tail.
// Passthrough stays in the gather phase (r13 placement: stores from
// just-loaded regs, drain under proj/LN/softmax).
__global__ __launch_bounds__(512, 4) void swin_mfma12(
    const float* __restrict__ lr, const float* __restrict__ ref,
    const float* __restrict__ qkv_w, const float* __restrict__ qkv_b,
    const float* __restrict__ ln_g, const float* __restrict__ ln_b,
    float* __restrict__ out, float* __restrict__ out1)
{
    __shared__ __align__(16) u16t s_wT[C3 * WTW];         // W^T [j][c] bf16, 16128 B (shared)
    __shared__ __align__(16) u16t s_y[2][YROWS * YW];     // per-window y, 2*17328 B
    __shared__ __align__(16) u16t s_P[2][3 * 32 * PW];    // per-window per-head P, 2*7680 B
    __shared__ __align__(16) u16t s_x1T[2][3 * 16 * PW];  // per-window v^T then x1^T, 2*3840 B
    __shared__ __align__(16) float s_ln[2][4][16][4];     // LN partials, 2048 B
    __shared__ __align__(16) float s_gb[3 * C3];          // bias | gamma | beta, 1728 B
    // total 77600 B -> 2 blocks/CU (16 waves)

    const int tid = threadIdx.x;
    const int wave = tid >> 6, lane = tid & 63;
    const int lm = lane & 15, g = lane >> 4;
    const int wh = wave >> 2;            // which of the 2 windows
    const int w4 = wave & 3;             // role within the window
    const int br = w4 >> 1, jh = w4 & 1;
    const int T0 = jh ? 4 : 0;           // tiles T0..T0+4 (tile 4 overlaps both halves)
    const bool gok = (g < 2);

    // ---- per-block staging: W^T, bias/ln params; zero pad rows + s_x1T ----
    for (int i = tid; i < CC * C3; i += 512) {
        int c = i / C3, j = i % C3;
        s_wT[j * WTW + c] = f2b(qkv_w[i]);
    }
    for (int i = tid; i < C3; i += 512) {
        s_gb[i] = qkv_b[i];
        s_gb[C3 + i] = ln_g[i];
        s_gb[2 * C3 + i] = ln_b[i];
    }
    for (int i = tid; i < 7 * YW; i += 512) {
        s_y[0][25 * YW + i] = 0;
        s_y[1][25 * YW + i] = 0;
    }
    for (int i = tid; i < 3 * 16 * PW; i += 512) {   // NaN-safety for vT pad cols (r15 lesson)
        s_x1T[0][i] = 0;
        s_x1T[1][i] = 0;
    }
    __syncthreads();

    const bf16x8 z8 = {0, 0, 0, 0, 0, 0, 0, 0};
    const f32x4  z4 = {0.f, 0.f, 0.f, 0.f};
    const float* xsrc = br ? ref : lr;

    for (int it = 0; it < ITERS; ++it) {
        const int wid = blockIdx.x * (2 * ITERS) + it * 2 + wh;
        const int bb = wid / (NWH * NWH);
        const int rr = wid % (NWH * NWH);
        const int bh = rr / NWH, bw = rr % NWH;

        // ---- X B-frags from global (col=lm -> x-row; k=8g+j); out1 fold on w4==3
        //      (stores issue from just-loaded registers; drain under proj/LN/softmax) ----
        bf16x8 xa[2], xb[2];
        #pragma unroll
        for (int s2 = 0; s2 < 2; ++s2) {
            int row = 16 * s2 + lm;                       // 0..31 (25..31 pad, masked later)
            int wi = row / WSZ, wj = row % WSZ;
            int hh = bh * WSZ + wi + SH; if (hh >= HDIM) hh -= HDIM;
            int ww = bw * WSZ + wj + SH; if (ww >= HDIM) ww -= HDIM;
            const float4* p4 = reinterpret_cast<const float4*>(
                xsrc + ((size_t)(bb * HDIM + hh) * HDIM + ww) * CC);
            float4 u = p4[2 * g], v = p4[2 * g + 1];      // k = 8g..8g+7
            bf16x8 t;
            t[0] = f2b(u.x); t[1] = f2b(u.y); t[2] = f2b(u.z); t[3] = f2b(u.w);
            t[4] = f2b(v.x); t[5] = f2b(v.y); t[6] = f2b(v.z); t[7] = f2b(v.w);
            xa[s2] = t;
            float4 u2, v2;
            if (gok) {
                u2 = p4[8 + 2 * g]; v2 = p4[9 + 2 * g];   // k = 32+8g..39+8g
                bf16x8 t2;
                t2[0] = f2b(u2.x); t2[1] = f2b(u2.y); t2[2] = f2b(u2.z); t2[3] = f2b(u2.w);
                t2[4] = f2b(v2.x); t2[5] = f2b(v2.y); t2[6] = f2b(v2.z); t2[7] = f2b(v2.w);
                xb[s2] = t2;
            } else xb[s2] = z8;
            if (w4 == 3 && row < 25) {                    // ref passthrough fold
                float4* o1 = reinterpret_cast<float4*>(
                    out1 + ((size_t)(bb * HDIM + hh) * HDIM + ww) * CC);
                o1[2 * g] = u; o1[2 * g + 1] = v;
                if (gok) { o1[8 + 2 * g] = u2; o1[9 + 2 * g] = v2; }
            }
        }

        // ---- projection: acc[tt][side] = bias + W^T . X (W from LDS, no spills) ----
        f32x4 acc[5][2];
        #pragma unroll
        for (int tt = 0; tt < 5; ++tt) {
            const int t = T0 + tt;
            bf16x8 w1 = *reinterpret_cast<const bf16x8*>(&s_wT[(16 * t + lm) * WTW + 8 * g]);
            bf16x8 w2 = *reinterpret_cast<const bf16x8*>(&s_wT[(16 * t + lm) * WTW + 32 + 8 * (g & 1)]);
            f32x4 bv = *reinterpret_cast<const f32x4*>(&s_gb[16 * t + 4 * g]);
            #pragma unroll
            for (int s2 = 0; s2 < 2; ++s2) {
                f32x4 a = bv;
                a = __builtin_amdgcn_mfma_f32_16x16x32_bf16(w1, xa[s2], a, 0, 0, 0);
                a = __builtin_amdgcn_mfma_f32_16x16x32_bf16(w2, xb[s2], a, 0, 0, 0);
                acc[tt][s2] = a;
            }
        }

        // ---- LN partial stats per x-row (jh=1 excludes overlap tile tt=0) ----
        float s0 = 0.f, q0 = 0.f, s1 = 0.f, q1 = 0.f;
        #pragma unroll
        for (int tt = 0; tt < 5; ++tt) {
            if (jh == 0 || tt > 0) {
                #pragma unroll
                for (int r2 = 0; r2 < 4; ++r2) {
                    float va = acc[tt][0][r2]; s0 += va; q0 += va * va;
                    float vb = acc[tt][1][r2]; s1 += vb; q1 += vb * vb;
                }
            }
        }
        s0 += __shfl_xor(s0, 16); s0 += __shfl_xor(s0, 32);
        q0 += __shfl_xor(q0, 16); q0 += __shfl_xor(q0, 32);
        s1 += __shfl_xor(s1, 16); s1 += __shfl_xor(s1, 32);
        q1 += __shfl_xor(q1, 16); q1 += __shfl_xor(q1, 32);
        if (lane < 16) {
            float4 w4v = make_float4(s0, q0, s1, q1);
            *reinterpret_cast<float4*>(&s_ln[wh][w4][lm][0]) = w4v;
        }
        __syncthreads();   // bar1 (also protects s_y(i-1) / s_ln / s_x1T from next writes)
        {
            float4 p = *reinterpret_cast<const float4*>(&s_ln[wh][w4 ^ 1][lm][0]);
            float S0 = s0 + p.x, Q0 = q0 + p.y, S1 = s1 + p.z, Q1 = q1 + p.w;
            float mu0 = S0 * (1.f / 144.f);
            float rs0 = rsqrtf(Q0 * (1.f / 144.f) - mu0 * mu0 + 1e-5f);
            float mu1 = S1 * (1.f / 144.f);
            float rs1 = rsqrtf(Q1 * (1.f / 144.f) - mu1 * mu1 + 1e-5f);
            #pragma unroll
            for (int tt = 0; tt < 5; ++tt) {
                const int t = T0 + tt;
                f32x4 gv = *reinterpret_cast<const f32x4*>(&s_gb[C3 + 16 * t + 4 * g]);
                f32x4 bv2 = *reinterpret_cast<const f32x4*>(&s_gb[2 * C3 + 16 * t + 4 * g]);
                #pragma unroll
                for (int r2 = 0; r2 < 4; ++r2) {
                    acc[tt][0][r2] = (acc[tt][0][r2] - mu0) * rs0 * gv[r2] + bv2[r2];
                    acc[tt][1][r2] = (acc[tt][1][r2] - mu1) * rs1 * gv[r2] + bv2[r2];
                }
            }
        }

        // ---- softmax over 25 rows (DPP reduce; no max pass); y + v^T writes ----
        #pragma unroll
        for (int tt = 0; tt < 5; ++tt) {
            const int t = T0 + tt;
            float pa[4], pb[4];
            #pragma unroll
            for (int r2 = 0; r2 < 4; ++r2) {
                float va = acc[tt][0][r2];                          // rows 0..15
                float vb = (lm < 9) ? acc[tt][1][r2] : -1e30f;      // rows 16..24 (+pad)
                float ea = __expf(va), eb = __expf(vb);
                float ss = dpp_add16(ea + eb);
                float inv = __builtin_amdgcn_rcpf(ss);
                pa[r2] = ea * inv; pb[r2] = eb * inv;
            }
            int colw = 16 * t + 4 * g;
            uint2 wv;
            wv.x = pk2(pa[0], pa[1]); wv.y = pk2(pa[2], pa[3]);
            *reinterpret_cast<uint2*>(&s_y[wh][(32 * br + lm) * YW + colw]) = wv;
            if (lm < 9) {
                wv.x = pk2(pb[0], pb[1]); wv.y = pk2(pb[2], pb[3]);
                *reinterpret_cast<uint2*>(&s_y[wh][(32 * br + 16 + lm) * YW + colw]) = wv;
            }
            // wave (br=1,jh=1): transpose-write v_ref into s_x1T (as v^T) for PV1.
            // m=25..31 stay zero (init) or stale-finite (x1); P[n][m>=25]==0 exactly.
            if (w4 == 3 && t >= 6) {
                u16t* vT = &s_x1T[wh][(t - 6) * 16 * PW];
                #pragma unroll
                for (int r2 = 0; r2 < 4; ++r2) {
                    vT[(4 * g + r2) * PW + lm] = f2b(pa[r2]);          // m = lm
                    if (lm < 9) vT[(4 * g + r2) * PW + 16 + lm] = f2b(pb[r2]);  // m = 16+lm
                }
            }
        }
        __syncthreads();   // bar2: y + v^T ready

        // ---- attention on waves w4<3 (head = w4); w4==3 idles (already stored out1) ----
        if (w4 < 3) {
            const int h = w4;
            const int ko = 8 * (g & 1);
            const bool lok = (lm < 9);
            const u16t* Y = s_y[wh];
            u16t* Ph = &s_P[wh][h * 32 * PW];
            u16t* Xh = &s_x1T[wh][h * 16 * PW];
            __builtin_amdgcn_s_setprio(1);
            // QK1: D[m][n] = k_ref[m].q_lr[n]
            bf16x8 ka0 = gok ? *reinterpret_cast<const bf16x8*>(&Y[(32 + lm) * YW + CC + 16 * h + ko]) : z8;
            bf16x8 ka1 = (gok && lok) ? *reinterpret_cast<const bf16x8*>(&Y[(48 + lm) * YW + CC + 16 * h + ko]) : z8;
            bf16x8 qb0 = *reinterpret_cast<const bf16x8*>(&Y[lm * YW + 16 * h + ko]);
            bf16x8 qb1 = *reinterpret_cast<const bf16x8*>(&Y[(16 + lm) * YW + 16 * h + ko]);   // pads zeroed
            f32x4 p00 = __builtin_amdgcn_mfma_f32_16x16x32_bf16(ka0, qb0, z4, 0, 0, 0);
            f32x4 p01 = __builtin_amdgcn_mfma_f32_16x16x32_bf16(ka0, qb1, z4, 0, 0, 0);
            f32x4 p10 = __builtin_amdgcn_mfma_f32_16x16x32_bf16(ka1, qb0, z4, 0, 0, 0);
            f32x4 p11 = __builtin_amdgcn_mfma_f32_16x16x32_bf16(ka1, qb1, z4, 0, 0, 0);
            uint2 wv;
            wv.x = pk2(p00[0], p00[1]); wv.y = pk2(p00[2], p00[3]);
            *reinterpret_cast<uint2*>(&Ph[lm * PW + 4 * g]) = wv;
            wv.x = pk2(p01[0], p01[1]); wv.y = pk2(p01[2], p01[3]);
            *reinterpret_cast<uint2*>(&Ph[(16 + lm) * PW + 4 * g]) = wv;
            wv.x = pk2(p10[0], p10[1]); wv.y = pk2(p10[2], p10[3]);
            *reinterpret_cast<uint2*>(&Ph[lm * PW + 16 + 4 * g]) = wv;
            wv.x = pk2(p11[0], p11[1]); wv.y = pk2(p11[2], p11[3]);
            *reinterpret_cast<uint2*>(&Ph[(16 + lm) * PW + 16 + 4 * g]) = wv;
            // PV1: D[n][dv] = P1[n][m].v[m][dv]; v^T via one ds_read_b128
            bf16x8 vfr = *reinterpret_cast<const bf16x8*>(&Xh[lm * PW + 8 * g]);
            bf16x8 a0 = *reinterpret_cast<const bf16x8*>(&Ph[lm * PW + 8 * g]);
            bf16x8 a1 = *reinterpret_cast<const bf16x8*>(&Ph[(16 + lm) * PW + 8 * g]);
            f32x4 x10 = __builtin_amdgcn_mfma_f32_16x16x32_bf16(a0, vfr, z4, 0, 0, 0);
            f32x4 x11 = __builtin_amdgcn_mfma_f32_16x16x32_bf16(a1, vfr, z4, 0, 0, 0);
            wv.x = pk2(x10[0], x10[1]); wv.y = pk2(x10[2], x10[3]);
            *reinterpret_cast<uint2*>(&Xh[lm * PW + 4 * g]) = wv;        // n = 4g+r2
            wv.x = pk2(x11[0], x11[1]); wv.y = pk2(x11[2], x11[3]);
            *reinterpret_cast<uint2*>(&Xh[lm * PW + 16 + 4 * g]) = wv;   // n = 16+4g+r2
            // QK2: D[m][n] = k_lr[m].q_ref[n]
            bf16x8 kb0 = gok ? *reinterpret_cast<const bf16x8*>(&Y[lm * YW + CC + 16 * h + ko]) : z8;
            bf16x8 kb1 = gok ? *reinterpret_cast<const bf16x8*>(&Y[(16 + lm) * YW + CC + 16 * h + ko]) : z8;
            bf16x8 qc0 = *reinterpret_cast<const bf16x8*>(&Y[(32 + lm) * YW + 16 * h + ko]);
            bf16x8 qc1 = lok ? *reinterpret_cast<const bf16x8*>(&Y[(48 + lm) * YW + 16 * h + ko]) : z8;
            p00 = __builtin_amdgcn_mfma_f32_16x16x32_bf16(kb0, qc0, z4, 0, 0, 0);
            p01 = __builtin_amdgcn_mfma_f32_16x16x32_bf16(kb0, qc1, z4, 0, 0, 0);
            p10 = __builtin_amdgcn_mfma_f32_16x16x32_bf16(kb1, qc0, z4, 0, 0, 0);
            p11 = __builtin_amdgcn_mfma_f32_16x16x32_bf16(kb1, qc1, z4, 0, 0, 0);
            wv.x = pk2(p00[0], p00[1]); wv.y = pk2(p00[2], p00[3]);
            *reinterpret_cast<uint2*>(&Ph[lm * PW + 4 * g]) = wv;
            wv.x = pk2(p01[0], p01[1]); wv.y = pk2(p01[2], p01[3]);
            *reinterpret_cast<uint2*>(&Ph[(16 + lm) * PW + 4 * g]) = wv;
            wv.x = pk2(p10[0], p10[1]); wv.y = pk2(p10[2], p10[3]);
            *reinterpret_cast<uint2*>(&Ph[lm * PW + 16 + 4 * g]) = wv;
            wv.x = pk2(p11[0], p11[1]); wv.y = pk2(p11[2], p11[3]);
            *reinterpret_cast<uint2*>(&Ph[(16 + lm) * PW + 16 + 4 * g]) = wv;
            // PV2: D[dv][n2] = x1T[dv][m].P2[n2][m]; store out0
            bf16x8 xv = *reinterpret_cast<const bf16x8*>(&Xh[lm * PW + 8 * g]);
            bf16x8 pb0 = *reinterpret_cast<const bf16x8*>(&Ph[lm * PW + 8 * g]);
            bf16x8 pb1 = *reinterpret_cast<const bf16x8*>(&Ph[(16 + lm) * PW + 8 * g]);
            f32x4 o0 = __builtin_amdgcn_mfma_f32_16x16x32_bf16(xv, pb0, z4, 0, 0, 0);
            f32x4 o1v = __builtin_amdgcn_mfma_f32_16x16x32_bf16(xv, pb1, z4, 0, 0, 0);
            __builtin_amdgcn_s_setprio(0);
            #pragma unroll
            for (int nt = 0; nt < 2; ++nt) {
                int n2 = 16 * nt + lm;
                if (n2 < 25) {
                    f32x4 ov = nt ? o1v : o0;
                    int wi2 = n2 / WSZ, wj2 = n2 % WSZ;
                    int oh = bh * WSZ + wi2 + SH; if (oh >= HDIM) oh -= HDIM;
                    int ow = bw * WSZ + wj2 + SH; if (ow >= HDIM) ow -= HDIM;
                    float4 o = make_float4(ov[0], ov[1], ov[2], ov[3]);
                    *reinterpret_cast<float4*>(
                        &out[((size_t)(bb * HDIM + oh) * HDIM + ow) * CC + 16 * h + 4 * g]) = o;
                }
            }
        }
        // no end-of-loop barrier: bar1 of next iteration protects s_y / s_ln / s_x1T
    }
}

extern "C" void kernel_launch(void* const* d_in, const int* in_sizes, int n_in,
                              void* d_out, int out_size, void* d_ws, size_t ws_size,
                              hipStream_t stream) {
    const float* lr    = (const float*)d_in[0];
    const float* ref   = (const float*)d_in[1];
    const float* qkv_w = (const float*)d_in[2];
    const float* qkv_b = (const float*)d_in[3];
    const float* ln_g  = (const float*)d_in[4];
    const float* ln_b  = (const float*)d_in[5];
    float* out = (float*)d_out;
    float* out1 = out + (size_t)out_size / 2;   // ref passthrough region

    const int n_blocks = 4 * NWH * NWH / (2 * ITERS);   // 6400
    swin_mfma12<<<n_blocks, 512, 0, stream>>>(lr, ref, qkv_w, qkv_b, ln_g, ln_b, out, out1);
}

// Round 19
// 263.881 us; speedup vs baseline: 1.5233x; 1.5233x over previous
//
#include <hip/hip_runtime.h>
#include <hip/hip_bf16.h>

typedef __hip_bfloat16 hbf16;
typedef unsigned short u16t;
typedef __attribute__((ext_vector_type(8))) short bf16x8;
typedef __attribute__((ext_vector_type(4))) float f32x4;

#define WSZ 5
#define CC 48
#define C3 144
#define HDIM 400
#define NWH 80
#define SH 2
#define ITERS 4      // windows per block = 2 * ITERS (r18 proved 4 is load-bearing)
#define YROWS 57
#define YW 152   // s_y row stride (halfwords); 304 B, mult 16, 2-way max
#define WTW 56   // s_wT row stride; 112 B, mult 16
#define PW 40    // s_P / s_x1T row stride; 80 B, mult 16

__device__ __forceinline__ u16t f2b(float x) {
    union { hbf16 h; u16t u; } c;
    c.h = __float2bfloat16(x);
    return c.u;
}
__device__ __forceinline__ unsigned pk2(float lo, float hi) {
    return ((unsigned)f2b(hi) << 16) | f2b(lo);
}
// 16-lane (DPP row) butterfly sum — pure VALU, no LDS pipe (verified r12/r13).
__device__ __forceinline__ float dpp_add16(float x) {
    int t;
    t = __builtin_amdgcn_update_dpp(0, __float_as_int(x), 0xB1, 0xF, 0xF, true);   // quad_perm xor1
    x += __int_as_float(t);
    t = __builtin_amdgcn_update_dpp(0, __float_as_int(x), 0x4E, 0xF, 0xF, true);   // quad_perm xor2
    x += __int_as_float(t);
    t = __builtin_amdgcn_update_dpp(0, __float_as_int(x), 0x141, 0xF, 0xF, true);  // row_half_mirror
    x += __int_as_float(t);
    t = __builtin_amdgcn_update_dpp(0, __float_as_int(x), 0x140, 0xF, 0xF, true);  // row_mirror
    x += __int_as_float(t);
    return x;
}

// r19 = r13 restored verbatim — FINAL configuration (reproduced twice:
// 264.6/264.7 µs total, 296.5 µs kernel, counters bit-stable).
// Falsification record bracketing this optimum:
//   r10/r12: register hoists/pipelining -> scratch spills (+0.5 GB HBM)
//   r14: 256-thr decoupled blocks -> occupancy 42->21%
//   r15: vT alias without init -> 0*NaN=NaN
//   r16: passthrough after bar2 -> +FETCH/+WRITE (loses reg-reuse + drain window)
//   r18: ITERS 4->2 + vT graft -> +79 MB staging FETCH, +244 MB WRITE
// 512-thread block = 2 windows (wh = wave>>2), 4 waves per window.
// Wave w4 = (branch=w4>>1, j-half=w4&1). Projection D = mfma(W^T, X):
// lane(lm,g) holds j=16t+4g+r2, x-row=lm(+16*side).
__global__ __launch_bounds__(512, 4) void swin_final(
    const float* __restrict__ lr, const float* __restrict__ ref,
    const float* __restrict__ qkv_w, const float* __restrict__ qkv_b,
    const float* __restrict__ ln_g, const float* __restrict__ ln_b,
    float* __restrict__ out, float* __restrict__ out1)
{
    __shared__ __align__(16) u16t s_wT[C3 * WTW];         // W^T [j][c] bf16, 16128 B (shared)
    __shared__ __align__(16) u16t s_y[2][YROWS * YW];     // per-window y, 2*17328 B
    __shared__ __align__(16) u16t s_P[2][3 * 32 * PW];    // per-window per-head P, 2*7680 B
    __shared__ __align__(16) u16t s_x1T[2][3 * 16 * PW];  // per-window x1^T, 2*3840 B
    __shared__ __align__(16) float s_ln[2][4][16][4];     // LN partials, 2048 B
    __shared__ __align__(16) float s_gb[3 * C3];          // bias | gamma | beta, 1728 B
    // total 77600 B -> 2 blocks/CU (16 waves)

    const int tid = threadIdx.x;
    const int wave = tid >> 6, lane = tid & 63;
    const int lm = lane & 15, g = lane >> 4;
    const int wh = wave >> 2;            // which of the 2 windows
    const int w4 = wave & 3;             // role within the window
    const int br = w4 >> 1, jh = w4 & 1;
    const int T0 = jh ? 4 : 0;           // tiles T0..T0+4 (tile 4 overlaps both halves)
    const bool gok = (g < 2);

    // ---- per-block staging: W^T, bias/ln params; zero pad rows 25..31 ----
    for (int i = tid; i < CC * C3; i += 512) {
        int c = i / C3, j = i % C3;
        s_wT[j * WTW + c] = f2b(qkv_w[i]);
    }
    for (int i = tid; i < C3; i += 512) {
        s_gb[i] = qkv_b[i];
        s_gb[C3 + i] = ln_g[i];
        s_gb[2 * C3 + i] = ln_b[i];
    }
    for (int i = tid; i < 7 * YW; i += 512) {
        s_y[0][25 * YW + i] = 0;
        s_y[1][25 * YW + i] = 0;
    }
    __syncthreads();

    const bf16x8 z8 = {0, 0, 0, 0, 0, 0, 0, 0};
    const f32x4  z4 = {0.f, 0.f, 0.f, 0.f};
    const float* xsrc = br ? ref : lr;

    for (int it = 0; it < ITERS; ++it) {
        const int wid = blockIdx.x * (2 * ITERS) + it * 2 + wh;
        const int bb = wid / (NWH * NWH);
        const int rr = wid % (NWH * NWH);
        const int bh = rr / NWH, bw = rr % NWH;

        // ---- X B-frags from global (col=lm -> x-row; k=8g+j); out1 fold on w4==3
        //      (stores issue from just-loaded registers; drain under proj/LN/softmax) ----
        bf16x8 xa[2], xb[2];
        #pragma unroll
        for (int s2 = 0; s2 < 2; ++s2) {
            int row = 16 * s2 + lm;                       // 0..31 (25..31 pad, masked later)
            int wi = row / WSZ, wj = row % WSZ;
            int hh = bh * WSZ + wi + SH; if (hh >= HDIM) hh -= HDIM;
            int ww = bw * WSZ + wj + SH; if (ww >= HDIM) ww -= HDIM;
            const float4* p4 = reinterpret_cast<const float4*>(
                xsrc + ((size_t)(bb * HDIM + hh) * HDIM + ww) * CC);
            float4 u = p4[2 * g], v = p4[2 * g + 1];      // k = 8g..8g+7
            bf16x8 t;
            t[0] = f2b(u.x); t[1] = f2b(u.y); t[2] = f2b(u.z); t[3] = f2b(u.w);
            t[4] = f2b(v.x); t[5] = f2b(v.y); t[6] = f2b(v.z); t[7] = f2b(v.w);
            xa[s2] = t;
            float4 u2, v2;
            if (gok) {
                u2 = p4[8 + 2 * g]; v2 = p4[9 + 2 * g];   // k = 32+8g..39+8g
                bf16x8 t2;
                t2[0] = f2b(u2.x); t2[1] = f2b(u2.y); t2[2] = f2b(u2.z); t2[3] = f2b(u2.w);
                t2[4] = f2b(v2.x); t2[5] = f2b(v2.y); t2[6] = f2b(v2.z); t2[7] = f2b(v2.w);
                xb[s2] = t2;
            } else xb[s2] = z8;
            if (w4 == 3 && row < 25) {                    // ref passthrough fold
                float4* o1 = reinterpret_cast<float4*>(
                    out1 + ((size_t)(bb * HDIM + hh) * HDIM + ww) * CC);
                o1[2 * g] = u; o1[2 * g + 1] = v;
                if (gok) { o1[8 + 2 * g] = u2; o1[9 + 2 * g] = v2; }
            }
        }

        // ---- projection: acc[tt][side] = bias + W^T . X (W from LDS, no spills) ----
        f32x4 acc[5][2];
        #pragma unroll
        for (int tt = 0; tt < 5; ++tt) {
            const int t = T0 + tt;
            bf16x8 w1 = *reinterpret_cast<const bf16x8*>(&s_wT[(16 * t + lm) * WTW + 8 * g]);
            bf16x8 w2 = *reinterpret_cast<const bf16x8*>(&s_wT[(16 * t + lm) * WTW + 32 + 8 * (g & 1)]);
            f32x4 bv = *reinterpret_cast<const f32x4*>(&s_gb[16 * t + 4 * g]);
            #pragma unroll
            for (int s2 = 0; s2 < 2; ++s2) {
                f32x4 a = bv;
                a = __builtin_amdgcn_mfma_f32_16x16x32_bf16(w1, xa[s2], a, 0, 0, 0);
                a = __builtin_amdgcn_mfma_f32_16x16x32_bf16(w2, xb[s2], a, 0, 0, 0);
                acc[tt][s2] = a;
            }
        }

        // ---- LN partial stats per x-row (jh=1 excludes overlap tile tt=0) ----
        float s0 = 0.f, q0 = 0.f, s1 = 0.f, q1 = 0.f;
        #pragma unroll
        for (int tt = 0; tt < 5; ++tt) {
            if (jh == 0 || tt > 0) {
                #pragma unroll
                for (int r2 = 0; r2 < 4; ++r2) {
                    float va = acc[tt][0][r2]; s0 += va; q0 += va * va;
                    float vb = acc[tt][1][r2]; s1 += vb; q1 += vb * vb;
                }
            }
        }
        s0 += __shfl_xor(s0, 16); s0 += __shfl_xor(s0, 32);
        q0 += __shfl_xor(q0, 16); q0 += __shfl_xor(q0, 32);
        s1 += __shfl_xor(s1, 16); s1 += __shfl_xor(s1, 32);
        q1 += __shfl_xor(q1, 16); q1 += __shfl_xor(q1, 32);
        if (lane < 16) {
            float4 w4v = make_float4(s0, q0, s1, q1);
            *reinterpret_cast<float4*>(&s_ln[wh][w4][lm][0]) = w4v;
        }
        __syncthreads();   // bar1 (also protects s_y(i-1) / s_ln from next writes)
        {
            float4 p = *reinterpret_cast<const float4*>(&s_ln[wh][w4 ^ 1][lm][0]);
            float S0 = s0 + p.x, Q0 = q0 + p.y, S1 = s1 + p.z, Q1 = q1 + p.w;
            float mu0 = S0 * (1.f / 144.f);
            float rs0 = rsqrtf(Q0 * (1.f / 144.f) - mu0 * mu0 + 1e-5f);
            float mu1 = S1 * (1.f / 144.f);
            float rs1 = rsqrtf(Q1 * (1.f / 144.f) - mu1 * mu1 + 1e-5f);
            #pragma unroll
            for (int tt = 0; tt < 5; ++tt) {
                const int t = T0 + tt;
                f32x4 gv = *reinterpret_cast<const f32x4*>(&s_gb[C3 + 16 * t + 4 * g]);
                f32x4 bv2 = *reinterpret_cast<const f32x4*>(&s_gb[2 * C3 + 16 * t + 4 * g]);
                #pragma unroll
                for (int r2 = 0; r2 < 4; ++r2) {
                    acc[tt][0][r2] = (acc[tt][0][r2] - mu0) * rs0 * gv[r2] + bv2[r2];
                    acc[tt][1][r2] = (acc[tt][1][r2] - mu1) * rs1 * gv[r2] + bv2[r2];
                }
            }
        }

        // ---- softmax over 25 rows (DPP 16-lane reduce; |LN out|<=~12 -> no max pass) ----
        #pragma unroll
        for (int tt = 0; tt < 5; ++tt) {
            const int t = T0 + tt;
            float pa[4], pb[4];
            #pragma unroll
            for (int r2 = 0; r2 < 4; ++r2) {
                float va = acc[tt][0][r2];                          // rows 0..15
                float vb = (lm < 9) ? acc[tt][1][r2] : -1e30f;      // rows 16..24 (+pad)
                float ea = __expf(va), eb = __expf(vb);
                float ss = dpp_add16(ea + eb);
                float inv = __builtin_amdgcn_rcpf(ss);
                pa[r2] = ea * inv; pb[r2] = eb * inv;
            }
            int colw = 16 * t + 4 * g;
            uint2 wv;
            wv.x = pk2(pa[0], pa[1]); wv.y = pk2(pa[2], pa[3]);
            *reinterpret_cast<uint2*>(&s_y[wh][(32 * br + lm) * YW + colw]) = wv;
            if (lm < 9) {
                wv.x = pk2(pb[0], pb[1]); wv.y = pk2(pb[2], pb[3]);
                *reinterpret_cast<uint2*>(&s_y[wh][(32 * br + 16 + lm) * YW + colw]) = wv;
            }
        }
        __syncthreads();   // bar2: y ready

        // ---- attention on waves w4<3 (head = w4); w4==3 idles (already stored out1) ----
        if (w4 < 3) {
            const int h = w4;
            const int ko = 8 * (g & 1);
            const bool lok = (lm < 9);
            const u16t* Y = s_y[wh];
            u16t* Ph = &s_P[wh][h * 32 * PW];
            u16t* Xh = &s_x1T[wh][h * 16 * PW];
            __builtin_amdgcn_s_setprio(1);
            // QK1: D[m][n] = k_ref[m].q_lr[n]
            bf16x8 ka0 = gok ? *reinterpret_cast<const bf16x8*>(&Y[(32 + lm) * YW + CC + 16 * h + ko]) : z8;
            bf16x8 ka1 = (gok && lok) ? *reinterpret_cast<const bf16x8*>(&Y[(48 + lm) * YW + CC + 16 * h + ko]) : z8;
            bf16x8 qb0 = *reinterpret_cast<const bf16x8*>(&Y[lm * YW + 16 * h + ko]);
            bf16x8 qb1 = *reinterpret_cast<const bf16x8*>(&Y[(16 + lm) * YW + 16 * h + ko]);   // pads zeroed
            f32x4 p00 = __builtin_amdgcn_mfma_f32_16x16x32_bf16(ka0, qb0, z4, 0, 0, 0);
            f32x4 p01 = __builtin_amdgcn_mfma_f32_16x16x32_bf16(ka0, qb1, z4, 0, 0, 0);
            f32x4 p10 = __builtin_amdgcn_mfma_f32_16x16x32_bf16(ka1, qb0, z4, 0, 0, 0);
            f32x4 p11 = __builtin_amdgcn_mfma_f32_16x16x32_bf16(ka1, qb1, z4, 0, 0, 0);
            uint2 wv;
            wv.x = pk2(p00[0], p00[1]); wv.y = pk2(p00[2], p00[3]);
            *reinterpret_cast<uint2*>(&Ph[lm * PW + 4 * g]) = wv;
            wv.x = pk2(p01[0], p01[1]); wv.y = pk2(p01[2], p01[3]);
            *reinterpret_cast<uint2*>(&Ph[(16 + lm) * PW + 4 * g]) = wv;
            wv.x = pk2(p10[0], p10[1]); wv.y = pk2(p10[2], p10[3]);
            *reinterpret_cast<uint2*>(&Ph[lm * PW + 16 + 4 * g]) = wv;
            wv.x = pk2(p11[0], p11[1]); wv.y = pk2(p11[2], p11[3]);
            *reinterpret_cast<uint2*>(&Ph[(16 + lm) * PW + 16 + 4 * g]) = wv;
            // PV1: D[n][dv] = P1[n][m].v[m][dv]; v gathered from y (guard m<25)
            bf16x8 vfr;
            #pragma unroll
            for (int j = 0; j < 8; ++j) {
                int m = 8 * g + j;
                vfr[j] = (m < 25) ? (short)Y[(32 + m) * YW + 96 + 16 * h + lm] : (short)0;
            }
            bf16x8 a0 = *reinterpret_cast<const bf16x8*>(&Ph[lm * PW + 8 * g]);
            bf16x8 a1 = *reinterpret_cast<const bf16x8*>(&Ph[(16 + lm) * PW + 8 * g]);
            f32x4 x10 = __builtin_amdgcn_mfma_f32_16x16x32_bf16(a0, vfr, z4, 0, 0, 0);
            f32x4 x11 = __builtin_amdgcn_mfma_f32_16x16x32_bf16(a1, vfr, z4, 0, 0, 0);
            wv.x = pk2(x10[0], x10[1]); wv.y = pk2(x10[2], x10[3]);
            *reinterpret_cast<uint2*>(&Xh[lm * PW + 4 * g]) = wv;        // n = 4g+r2
            wv.x = pk2(x11[0], x11[1]); wv.y = pk2(x11[2], x11[3]);
            *reinterpret_cast<uint2*>(&Xh[lm * PW + 16 + 4 * g]) = wv;   // n = 16+4g+r2
            // QK2: D[m][n] = k_lr[m].q_ref[n]
            bf16x8 kb0 = gok ? *reinterpret_cast<const bf16x8*>(&Y[lm * YW + CC + 16 * h + ko]) : z8;
            bf16x8 kb1 = gok ? *reinterpret_cast<const bf16x8*>(&Y[(16 + lm) * YW + CC + 16 * h + ko]) : z8;
            bf16x8 qc0 = *reinterpret_cast<const bf16x8*>(&Y[(32 + lm) * YW + 16 * h + ko]);
            bf16x8 qc1 = lok ? *reinterpret_cast<const bf16x8*>(&Y[(48 + lm) * YW + 16 * h + ko]) : z8;
            p00 = __builtin_amdgcn_mfma_f32_16x16x32_bf16(kb0, qc0, z4, 0, 0, 0);
            p01 = __builtin_amdgcn_mfma_f32_16x16x32_bf16(kb0, qc1, z4, 0, 0, 0);
            p10 = __builtin_amdgcn_mfma_f32_16x16x32_bf16(kb1, qc0, z4, 0, 0, 0);
            p11 = __builtin_amdgcn_mfma_f32_16x16x32_bf16(kb1, qc1, z4, 0, 0, 0);
            wv.x = pk2(p00[0], p00[1]); wv.y = pk2(p00[2], p00[3]);
            *reinterpret_cast<uint2*>(&Ph[lm * PW + 4 * g]) = wv;
            wv.x = pk2(p01[0], p01[1]); wv.y = pk2(p01[2], p01[3]);
            *reinterpret_cast<uint2*>(&Ph[(16 + lm) * PW + 4 * g]) = wv;
            wv.x = pk2(p10[0], p10[1]); wv.y = pk2(p10[2], p10[3]);
            *reinterpret_cast<uint2*>(&Ph[lm * PW + 16 + 4 * g]) = wv;
            wv.x = pk2(p11[0], p11[1]); wv.y = pk2(p11[2], p11[3]);
            *reinterpret_cast<uint2*>(&Ph[(16 + lm) * PW + 16 + 4 * g]) = wv;
            // PV2: D[dv][n2] = x1T[dv][m].P2[n2][m]; store out0
            bf16x8 xv = *reinterpret_cast<const bf16x8*>(&Xh[lm * PW + 8 * g]);
            bf16x8 pb0 = *reinterpret_cast<const bf16x8*>(&Ph[lm * PW + 8 * g]);
            bf16x8 pb1 = *reinterpret_cast<const bf16x8*>(&Ph[(16 + lm) * PW + 8 * g]);
            f32x4 o0 = __builtin_amdgcn_mfma_f32_16x16x32_bf16(xv, pb0, z4, 0, 0, 0);
            f32x4 o1v = __builtin_amdgcn_mfma_f32_16x16x32_bf16(xv, pb1, z4, 0, 0, 0);
            __builtin_amdgcn_s_setprio(0);
            #pragma unroll
            for (int nt = 0; nt < 2; ++nt) {
                int n2 = 16 * nt + lm;
                if (n2 < 25) {
                    f32x4 ov = nt ? o1v : o0;
                    int wi2 = n2 / WSZ, wj2 = n2 % WSZ;
                    int oh = bh * WSZ + wi2 + SH; if (oh >= HDIM) oh -= HDIM;
                    int ow = bw * WSZ + wj2 + SH; if (ow >= HDIM) ow -= HDIM;
                    float4 o = make_float4(ov[0], ov[1], ov[2], ov[3]);
                    *reinterpret_cast<float4*>(
                        &out[((size_t)(bb * HDIM + oh) * HDIM + ow) * CC + 16 * h + 4 * g]) = o;
                }
            }
        }
        // no end-of-loop barrier: bar1 of next iteration protects s_y / s_ln
    }
}

extern "C" void kernel_launch(void* const* d_in, const int* in_sizes, int n_in,
                              void* d_out, int out_size, void* d_ws, size_t ws_size,
                              hipStream_t stream) {
    const float* lr    = (const float*)d_in[0];
    const float* ref   = (const float*)d_in[1];
    const float* qkv_w = (const float*)d_in[2];
    const float* qkv_b = (const float*)d_in[3];
    const float* ln_g  = (const float*)d_in[4];
    const float* ln_b  = (const float*)d_in[5];
    float* out = (float*)d_out;
    float* out1 = out + (size_t)out_size / 2;   // ref passthrough region

    const int n_blocks = 4 * NWH * NWH / (2 * ITERS);   // 3200
    swin_final<<<n_blocks, 512, 0, stream>>>(lr, ref, qkv_w, qkv_b, ln_g, ln_b, out, out1);
}